// Round 12
// baseline (331.084 us; speedup 1.0000x reference)
//
#include <hip/hip_runtime.h>
#include <hip/hip_bf16.h>
#include <stdint.h>

// Problem constants (PointerGenNetwork): T=64 B=32 S=400 V=32000 D=1536
#define T_DIM 64
#define B_DIM 32
#define S_DIM 400
#define V_DIM 32000
#define D_DIM 1536
#define M_DIM (T_DIM * B_DIM)   // 2048

typedef __attribute__((ext_vector_type(8))) short bf16x8;
typedef __attribute__((ext_vector_type(4))) float f32x4;

#define MEMFENCE asm volatile("" ::: "memory")
#define BARRIER() do { MEMFENCE; __builtin_amdgcn_s_barrier(); MEMFENCE; } while (0)

// ---------------- helpers ----------------

static __device__ __forceinline__ unsigned short f2bf(float x) {
    union { float f; uint32_t u; } v; v.f = x;
    uint32_t r = (v.u + 0x7FFFu + ((v.u >> 16) & 1u)) >> 16;   // RNE f32->bf16
    return (unsigned short)r;
}

static __device__ __forceinline__ void gload_lds16(const void* g, void* l) {
    __builtin_amdgcn_global_load_lds(
        (const __attribute__((address_space(1))) uint32_t*)g,
        (__attribute__((address_space(3))) uint32_t*)l,
        16, 0, 0);
}

// ---------------- pre-pass: W (K x V fp32) -> Wt (V x K bf16), fused h -> bf16 ----------------
// r11 measured ~105us vs 50us BW floor; invariant across LDS-conflict fixes =>
// DRAM/L2 locality of the 256B-per-row-visit W read is the suspect. This
// version: 256k x 128v tile (LDS 66.5KB, 2 blocks/CU) -> 512B-contiguous
// reads AND 512B-contiguous writes. Odd-dword stride 130 bounds transpose
// reads at <=8-way (~4us total). ushort2-pair reads serve 2 output v-rows.

__global__ __launch_bounds__(512, 2)
void convT_W_h(const float* __restrict__ W, unsigned short* __restrict__ Wt,
               const float* __restrict__ h, unsigned short* __restrict__ hb) {
    __shared__ unsigned short lds[256 * 130];   // 66,560 B
    const int k0 = blockIdx.x * 256;            // 1536/256 = 6
    const int v0 = blockIdx.y * 128;            // 32000/128 = 250
    const int tid = threadIdx.x;

    // fused h conversion: 786432 float4s over 1500 blocks x 512 threads
    {
        const int nblk = gridDim.x * gridDim.y;
        const int bidl = blockIdx.y * gridDim.x + blockIdx.x;
        const size_t n4 = (size_t)M_DIM * D_DIM / 4;
        for (size_t i = (size_t)bidl * 512 + tid; i < n4; i += (size_t)nblk * 512) {
            const float4 v = ((const float4*)h)[i];
            ushort4 o;
            o.x = f2bf(v.x); o.y = f2bf(v.y); o.z = f2bf(v.z); o.w = f2bf(v.w);
            ((ushort4*)hb)[i] = o;
        }
    }

    // stage W tile: 16 passes; per pass a wave's 32-lane half reads 512B
    // contiguous from one k-row (lanes 0..31 -> v-cols cc..cc+124).
    const int rr = tid >> 5;           // 0..15
    const int cc = (tid & 31) * 4;     // 0..124
    #pragma unroll
    for (int p = 0; p < 16; ++p) {
        const int r = p * 16 + rr;     // 0..255
        const float4 v = *(const float4*)&W[(size_t)(k0 + r) * V_DIM + v0 + cc];
        unsigned short* q = &lds[r * 130 + cc];
        ushort2 lo, hi;
        lo.x = f2bf(v.x); lo.y = f2bf(v.y);
        hi.x = f2bf(v.z); hi.y = f2bf(v.w);
        *(ushort2*)(q + 0) = lo;       // 4B-aligned (260*r + 2*cc, both /4)
        *(ushort2*)(q + 2) = hi;
    }
    __syncthreads();

    // output: 4 units/thread. unit = u*512+tid; kc = unit&31 (8-k chunk),
    // n2 = unit>>5 (v-row pair). Per store instruction 32 consecutive lanes
    // cover kc 0..31 -> 512B contiguous along k at one v-row.
    #pragma unroll
    for (int u = 0; u < 4; ++u) {
        const int unit = u * 512 + tid;
        const int kc = unit & 31;
        const int n2 = unit >> 5;      // 0..63
        const int kk = kc * 8;
        const int n = n2 * 2;
        union { bf16x8 v; unsigned short s[8]; } ra, rb;
        #pragma unroll
        for (int j = 0; j < 8; ++j) {
            const ushort2 pr = *(const ushort2*)&lds[(kk + j) * 130 + n];
            ra.s[j] = pr.x;
            rb.s[j] = pr.y;
        }
        *(bf16x8*)&Wt[(size_t)(v0 + n + 0) * D_DIM + k0 + kk] = ra.v;
        *(bf16x8*)&Wt[(size_t)(v0 + n + 1) * D_DIM + k0 + kk] = rb.v;
    }
}

// ---------------- main GEMM: r5/r10 consolidated best (221us, MfmaUtil 40%, 0 conflicts) ----------------
// A: M x K bf16 row-major. Bt: N x K bf16 row-major.
// BK=64. A double-buffered (2x32KB), B ring-3 (3x32KB) => 160KB LDS, 1 block/CU.
// Per K-tile: 4 phases (ks,mh), each = {barrier; ds_read 4-8 b128; stage 1
// half-tile (2 x global_load_lds); setprio(1); 16 MFMA; setprio(0); barrier}.
// Stage order during tile t: A0(t+1), A1(t+1), B0(t+2), B1(t+2).
// Gate once per K-tile before phase 0: vmcnt(4) [in-order retirement: A(t)
// resident, only B(t+1)'s 4 loads in flight]; vmcnt(0) only at the last tile.
// LDS swizzle (row&7)<<4 both-sides; XCD-bijective block swizzle (1000%8==0).

#define BM3 256
#define BN3 256
#define BK3 64
#define NKT3 (D_DIM / BK3)   // 24

__global__ __launch_bounds__(512, 2)
void gemm_8phase(const unsigned short* __restrict__ A,
                 const unsigned short* __restrict__ Bt,
                 const float* __restrict__ bias,
                 const float* __restrict__ p_gen,
                 float* __restrict__ out) {
    __shared__ char lds[163840];   // A: 2x32KB @0 ; B: 3x32KB @65536

    const int bid = blockIdx.x;
    const int swz = (bid & 7) * 125 + (bid >> 3);
    const int m0 = (swz & 7) * BM3;    // 8 m-tiles (fastest: B-panel L2 reuse/XCD)
    const int n0 = (swz >> 3) * BN3;   // 125 n-tiles

    const int tid = threadIdx.x;
    const int lane = tid & 63;
    const int wid = tid >> 6;
    const int wr = wid >> 2;       // 0..1 -> rows wr*128 + [0,128)
    const int wc = wid & 3;        // 0..3 -> cols wc*64 + [0,64)
    const int rq = lane & 15;
    const int kq = lane >> 4;      // 0..3

    // ---- staging geometry: half-tile = 128 rows x 128B = 16KB; per thread 2x16B.
    int stO[2], stRow[2], stCol[2];
    #pragma unroll
    for (int j = 0; j < 2; ++j) {
        const int o = tid * 16 + j * 8192;
        stO[j] = o;
        stRow[j] = o >> 7;                                 // 0..127 within half
        stCol[j] = (o & 127) ^ (((o >> 7) & 7) << 4);      // swizzled k-byte
    }

    auto stageA = [&](int t, int half) {                   // -> bufA (t&1)
        char* dst = lds + (t & 1) * 32768 + half * 16384;
        #pragma unroll
        for (int j = 0; j < 2; ++j) {
            const char* src = (const char*)A
                + (size_t)(m0 + half * 128 + stRow[j]) * (D_DIM * 2)
                + t * (BK3 * 2) + stCol[j];
            gload_lds16(src, dst + stO[j]);
        }
    };
    auto stageB = [&](int t, int half) {                   // -> bufB (t%3)
        char* dst = lds + 65536 + (t % 3) * 32768 + half * 16384;
        #pragma unroll
        for (int j = 0; j < 2; ++j) {
            const char* src = (const char*)Bt
                + (size_t)(n0 + half * 128 + stRow[j]) * (D_DIM * 2)
                + t * (BK3 * 2) + stCol[j];
            gload_lds16(src, dst + stO[j]);
        }
    };

    // ---- fragment ds_read byte offsets (within a 32KB tile buffer), swizzled
    int aOff[2][2][4], bOff[2][4];
    #pragma unroll
    for (int ks = 0; ks < 2; ++ks) {
        const int kb = ks * 64 + kq * 16;
        #pragma unroll
        for (int mh = 0; mh < 2; ++mh)
            #pragma unroll
            for (int mi = 0; mi < 4; ++mi) {
                const int row = wr * 128 + mh * 64 + mi * 16 + rq;
                aOff[ks][mh][mi] = row * 128 + (kb ^ ((row & 7) << 4));
            }
        #pragma unroll
        for (int nj = 0; nj < 4; ++nj) {
            const int row = wc * 64 + nj * 16 + rq;
            bOff[ks][nj] = row * 128 + (kb ^ ((row & 7) << 4));
        }
    }

    f32x4 acc[8][4] = {};
    bf16x8 aF[4], bF[4];

    // ---- prologue: A0(0) A1(0) B0(0) B1(0) B0(1) B1(1)  (12 loads)
    stageA(0, 0); stageA(0, 1);
    stageB(0, 0); stageB(0, 1);
    stageB(1, 0); stageB(1, 1);

    for (int t = 0; t < NKT3; ++t) {
        const char* bufA = lds + (t & 1) * 32768;
        const char* bufB = lds + 65536 + (t % 3) * 32768;

        // once-per-K-tile gate (before phase 0's barrier)
        if (t == NKT3 - 1) { asm volatile("s_waitcnt vmcnt(0)" ::: "memory"); }
        else               { asm volatile("s_waitcnt vmcnt(4)" ::: "memory"); }

        #pragma unroll
        for (int ph = 0; ph < 4; ++ph) {
            const int ks = ph >> 1;        // 0,0,1,1
            const int mh = ph & 1;         // 0,1,0,1

            BARRIER();
            // ds reads for THIS phase
            #pragma unroll
            for (int i = 0; i < 4; ++i)
                aF[i] = *(const bf16x8*)(bufA + aOff[ks][mh][i]);
            if (mh == 0) {
                #pragma unroll
                for (int nj = 0; nj < 4; ++nj)
                    bF[nj] = *(const bf16x8*)(bufB + bOff[ks][nj]);
            }
            // stage 1 half-tile for the pipeline
            if (ph < 2)      { if (t + 1 < NKT3) stageA(t + 1, ph); }
            else             { if (t + 2 < NKT3) stageB(t + 2, ph - 2); }

            __builtin_amdgcn_s_setprio(1);
            #pragma unroll
            for (int i = 0; i < 4; ++i)
                #pragma unroll
                for (int nj = 0; nj < 4; ++nj)
                    acc[mh * 4 + i][nj] = __builtin_amdgcn_mfma_f32_16x16x32_bf16(
                        aF[i], bF[nj], acc[mh * 4 + i][nj], 0, 0, 0);
            __builtin_amdgcn_s_setprio(0);
            BARRIER();
        }
    }

    // ---- epilogue: C/D layout col=lane&15, row=(lane>>4)*4+reg
    const int rr4 = (lane >> 4) * 4;
    #pragma unroll
    for (int mi = 0; mi < 8; ++mi) {
        #pragma unroll
        for (int r = 0; r < 4; ++r) {
            const int m = m0 + wr * 128 + (mi >> 2) * 64 + (mi & 3) * 16 + rr4 + r;
            const float pgv = p_gen[m];
            #pragma unroll
            for (int nj = 0; nj < 4; ++nj) {
                const int n = n0 + wc * 64 + nj * 16 + rq;
                out[(size_t)m * V_DIM + n] = pgv * (acc[mi][nj][r] + bias[n]);
            }
        }
    }
}

// ---------------- scatter: out[t,b,post[s,b]] += (1-pg[t,b]) * att[t,b,s] ----------------

__global__ void scatter_att(const float* __restrict__ att, const float* __restrict__ p_gen,
                            const int* __restrict__ post, float* __restrict__ out) {
    const int tb = blockIdx.x;             // t*B + b
    const int b = tb & (B_DIM - 1);
    const float g = 1.0f - p_gen[tb];
    float* o = out + (size_t)tb * V_DIM;
    const float* a = att + (size_t)tb * S_DIM;
    for (int s = threadIdx.x; s < S_DIM; s += blockDim.x) {
        atomicAdd(&o[post[s * B_DIM + b]], g * a[s]);
    }
}

// ---------------- fallback (ws too small): fp32 vector GEMM ----------------

#define FB_MT 16
__global__ __launch_bounds__(256)
void gemm_naive(const float* __restrict__ h, const float* __restrict__ W,
                const float* __restrict__ bias, const float* __restrict__ pg,
                float* __restrict__ out) {
    const int mb = blockIdx.y;
    const int v = blockIdx.x * 256 + threadIdx.x;
    __shared__ float hs[FB_MT][128];
    float acc[FB_MT] = {};
    for (int k0 = 0; k0 < D_DIM; k0 += 128) {
        for (int i = threadIdx.x; i < FB_MT * 128; i += 256)
            hs[i >> 7][i & 127] = h[(size_t)(mb * FB_MT + (i >> 7)) * D_DIM + k0 + (i & 127)];
        __syncthreads();
        for (int kk = 0; kk < 128; ++kk) {
            const float wv = W[(size_t)(k0 + kk) * V_DIM + v];
            #pragma unroll
            for (int i = 0; i < FB_MT; ++i) acc[i] += hs[i][kk] * wv;
        }
        __syncthreads();
    }
    #pragma unroll
    for (int i = 0; i < FB_MT; ++i) {
        const int m = mb * FB_MT + i;
        out[(size_t)m * V_DIM + v] = pg[m] * (acc[i] + bias[v]);
    }
}

// ---------------- launcher ----------------

extern "C" void kernel_launch(void* const* d_in, const int* in_sizes, int n_in,
                              void* d_out, int out_size, void* d_ws, size_t ws_size,
                              hipStream_t stream) {
    const float* h    = (const float*)d_in[0];   // (T,B,D)
    const float* W    = (const float*)d_in[1];   // (D,V)
    const float* bias = (const float*)d_in[2];   // (V,)
    const float* att  = (const float*)d_in[3];   // (T,B,S)
    const float* pg   = (const float*)d_in[4];   // (T,B,1)
    const int*   post = (const int*)d_in[5];     // (S,B)
    float* out = (float*)d_out;                  // (T,B,V) fp32

    const size_t wt_bytes = (size_t)V_DIM * D_DIM * 2;   // 98,304,000
    const size_t hb_bytes = (size_t)M_DIM * D_DIM * 2;   //  6,291,456

    if (ws_size >= wt_bytes + hb_bytes) {
        unsigned short* Wt = (unsigned short*)d_ws;
        unsigned short* hb = (unsigned short*)((char*)d_ws + wt_bytes);
        dim3 tg(D_DIM / 256, V_DIM / 128);   // 6 x 250
        convT_W_h<<<tg, 512, 0, stream>>>(W, Wt, h, hb);
        gemm_8phase<<<(M_DIM / BM3) * (V_DIM / BN3), 512, 0, stream>>>(hb, Wt, bias, pg, out);
    } else {
        dim3 fg(V_DIM / 256, M_DIM / FB_MT);
        gemm_naive<<<fg, 256, 0, stream>>>(h, W, bias, pg, out);
    }

    scatter_att<<<M_DIM, 256, 0, stream>>>(att, pg, post, out);
}

// Round 15
// 328.296 us; speedup vs baseline: 1.0085x; 1.0085x over previous
//
#include <hip/hip_runtime.h>
#include <hip/hip_bf16.h>
#include <stdint.h>

// Problem constants (PointerGenNetwork): T=64 B=32 S=400 V=32000 D=1536
#define T_DIM 64
#define B_DIM 32
#define S_DIM 400
#define V_DIM 32000
#define D_DIM 1536
#define M_DIM (T_DIM * B_DIM)   // 2048

typedef __attribute__((ext_vector_type(8))) short bf16x8;
typedef __attribute__((ext_vector_type(4))) float f32x4;

#define MEMFENCE asm volatile("" ::: "memory")
#define BARRIER() do { MEMFENCE; __builtin_amdgcn_s_barrier(); MEMFENCE; } while (0)

// ---------------- helpers ----------------

static __device__ __forceinline__ unsigned short f2bf(float x) {
    union { float f; uint32_t u; } v; v.f = x;
    uint32_t r = (v.u + 0x7FFFu + ((v.u >> 16) & 1u)) >> 16;   // RNE f32->bf16
    return (unsigned short)r;
}

static __device__ __forceinline__ void gload_lds16(const void* g, void* l) {
    __builtin_amdgcn_global_load_lds(
        (const __attribute__((address_space(1))) uint32_t*)g,
        (__attribute__((address_space(3))) uint32_t*)l,
        16, 0, 0);
}

// ---------------- pre-pass: W (K x V fp32) -> Wt (V x K bf16), fused h -> bf16 ----------------
// ~105us measured, invariant across 5 tile/stride structures (2x the 52us copy
// floor) -- bound by transpose locality (128KB row stride), not LDS/instr count.

__global__ __launch_bounds__(256)
void convT_W_h(const float* __restrict__ W, unsigned short* __restrict__ Wt,
               const float* __restrict__ h, unsigned short* __restrict__ hb) {
    __shared__ unsigned short lds[64 * 66];   // 64x64 tile, padded stride 66
    const int k0 = blockIdx.x * 64;           // 1536/64 = 24
    const int v0 = blockIdx.y * 64;           // 32000/64 = 500
    const int tid = threadIdx.x;
    const int rr = tid >> 4;                  // 0..15
    const int cc = (tid & 15) * 4;            // 0..60

    // fused h conversion: 786432 float4s spread over all 12000 blocks
    {
        const int nblk = gridDim.x * gridDim.y;
        const int bidl = blockIdx.y * gridDim.x + blockIdx.x;
        const size_t n4 = (size_t)M_DIM * D_DIM / 4;
        for (size_t i = (size_t)bidl * 256 + tid; i < n4; i += (size_t)nblk * 256) {
            const float4 v = ((const float4*)h)[i];
            ushort4 o;
            o.x = f2bf(v.x); o.y = f2bf(v.y); o.z = f2bf(v.z); o.w = f2bf(v.w);
            ((ushort4*)hb)[i] = o;
        }
    }

    #pragma unroll
    for (int p = 0; p < 4; ++p) {
        const int r = p * 16 + rr;
        const float4 v = *(const float4*)&W[(size_t)(k0 + r) * V_DIM + v0 + cc];
        unsigned short* q = &lds[r * 66 + cc];
        q[0] = f2bf(v.x); q[1] = f2bf(v.y); q[2] = f2bf(v.z); q[3] = f2bf(v.w);
    }
    __syncthreads();
    #pragma unroll
    for (int p = 0; p < 4; ++p) {
        const int n = p * 16 + rr;
        ushort4 o;
        o.x = lds[(cc + 0) * 66 + n];
        o.y = lds[(cc + 1) * 66 + n];
        o.z = lds[(cc + 2) * 66 + n];
        o.w = lds[(cc + 3) * 66 + n];
        *(ushort4*)&Wt[(size_t)(v0 + n) * D_DIM + k0 + cc] = o;
    }
}

// ---------------- main GEMM: session optimum (222us, MfmaUtil 40%, 0 conflicts, 907 TF) ----------------
// A: M x K bf16 row-major. Bt: N x K bf16 row-major.
// BK=64. A double-buffered (2x32KB), B ring-3 (3x32KB) => 160KB LDS, 1 block/CU.
// Per K-tile: 4 phases (ks,mh), each = {barrier; ds_read 4-8 b128; stage 1
// half-tile (2 x global_load_lds); setprio(1); 16 MFMA; setprio(0); barrier}.
// Stage order during tile t: A0(t+1), A1(t+1), B0(t+2), B1(t+2).
// Gate once per K-tile before phase 0: vmcnt(4) [in-order retirement: A(t)
// resident, only B(t+1)'s 4 loads in flight]; vmcnt(0) only at the last tile.
// LDS swizzle (row&7)<<4 both-sides; XCD-bijective block swizzle (1000%8==0).

#define BM3 256
#define BN3 256
#define BK3 64
#define NKT3 (D_DIM / BK3)   // 24

__global__ __launch_bounds__(512, 2)
void gemm_8phase(const unsigned short* __restrict__ A,
                 const unsigned short* __restrict__ Bt,
                 const float* __restrict__ bias,
                 const float* __restrict__ p_gen,
                 float* __restrict__ out) {
    __shared__ char lds[163840];   // A: 2x32KB @0 ; B: 3x32KB @65536

    const int bid = blockIdx.x;
    const int swz = (bid & 7) * 125 + (bid >> 3);
    const int m0 = (swz & 7) * BM3;    // 8 m-tiles (fastest: B-panel L2 reuse/XCD)
    const int n0 = (swz >> 3) * BN3;   // 125 n-tiles

    const int tid = threadIdx.x;
    const int lane = tid & 63;
    const int wid = tid >> 6;
    const int wr = wid >> 2;       // 0..1 -> rows wr*128 + [0,128)
    const int wc = wid & 3;        // 0..3 -> cols wc*64 + [0,64)
    const int rq = lane & 15;
    const int kq = lane >> 4;      // 0..3

    // ---- staging geometry: half-tile = 128 rows x 128B = 16KB; per thread 2x16B.
    int stO[2], stRow[2], stCol[2];
    #pragma unroll
    for (int j = 0; j < 2; ++j) {
        const int o = tid * 16 + j * 8192;
        stO[j] = o;
        stRow[j] = o >> 7;                                 // 0..127 within half
        stCol[j] = (o & 127) ^ (((o >> 7) & 7) << 4);      // swizzled k-byte
    }

    auto stageA = [&](int t, int half) {                   // -> bufA (t&1)
        char* dst = lds + (t & 1) * 32768 + half * 16384;
        #pragma unroll
        for (int j = 0; j < 2; ++j) {
            const char* src = (const char*)A
                + (size_t)(m0 + half * 128 + stRow[j]) * (D_DIM * 2)
                + t * (BK3 * 2) + stCol[j];
            gload_lds16(src, dst + stO[j]);
        }
    };
    auto stageB = [&](int t, int half) {                   // -> bufB (t%3)
        char* dst = lds + 65536 + (t % 3) * 32768 + half * 16384;
        #pragma unroll
        for (int j = 0; j < 2; ++j) {
            const char* src = (const char*)Bt
                + (size_t)(n0 + half * 128 + stRow[j]) * (D_DIM * 2)
                + t * (BK3 * 2) + stCol[j];
            gload_lds16(src, dst + stO[j]);
        }
    };

    // ---- fragment ds_read byte offsets (within a 32KB tile buffer), swizzled
    int aOff[2][2][4], bOff[2][4];
    #pragma unroll
    for (int ks = 0; ks < 2; ++ks) {
        const int kb = ks * 64 + kq * 16;
        #pragma unroll
        for (int mh = 0; mh < 2; ++mh)
            #pragma unroll
            for (int mi = 0; mi < 4; ++mi) {
                const int row = wr * 128 + mh * 64 + mi * 16 + rq;
                aOff[ks][mh][mi] = row * 128 + (kb ^ ((row & 7) << 4));
            }
        #pragma unroll
        for (int nj = 0; nj < 4; ++nj) {
            const int row = wc * 64 + nj * 16 + rq;
            bOff[ks][nj] = row * 128 + (kb ^ ((row & 7) << 4));
        }
    }

    f32x4 acc[8][4] = {};
    bf16x8 aF[4], bF[4];

    // ---- prologue: A0(0) A1(0) B0(0) B1(0) B0(1) B1(1)  (12 loads)
    stageA(0, 0); stageA(0, 1);
    stageB(0, 0); stageB(0, 1);
    stageB(1, 0); stageB(1, 1);

    for (int t = 0; t < NKT3; ++t) {
        const char* bufA = lds + (t & 1) * 32768;
        const char* bufB = lds + 65536 + (t % 3) * 32768;

        // once-per-K-tile gate (before phase 0's barrier)
        if (t == NKT3 - 1) { asm volatile("s_waitcnt vmcnt(0)" ::: "memory"); }
        else               { asm volatile("s_waitcnt vmcnt(4)" ::: "memory"); }

        #pragma unroll
        for (int ph = 0; ph < 4; ++ph) {
            const int ks = ph >> 1;        // 0,0,1,1
            const int mh = ph & 1;         // 0,1,0,1

            BARRIER();
            // ds reads for THIS phase
            #pragma unroll
            for (int i = 0; i < 4; ++i)
                aF[i] = *(const bf16x8*)(bufA + aOff[ks][mh][i]);
            if (mh == 0) {
                #pragma unroll
                for (int nj = 0; nj < 4; ++nj)
                    bF[nj] = *(const bf16x8*)(bufB + bOff[ks][nj]);
            }
            // stage 1 half-tile for the pipeline
            if (ph < 2)      { if (t + 1 < NKT3) stageA(t + 1, ph); }
            else             { if (t + 2 < NKT3) stageB(t + 2, ph - 2); }

            __builtin_amdgcn_s_setprio(1);
            #pragma unroll
            for (int i = 0; i < 4; ++i)
                #pragma unroll
                for (int nj = 0; nj < 4; ++nj)
                    acc[mh * 4 + i][nj] = __builtin_amdgcn_mfma_f32_16x16x32_bf16(
                        aF[i], bF[nj], acc[mh * 4 + i][nj], 0, 0, 0);
            __builtin_amdgcn_s_setprio(0);
            BARRIER();
        }
    }

    // ---- epilogue: C/D layout col=lane&15, row=(lane>>4)*4+reg
    const int rr4 = (lane >> 4) * 4;
    #pragma unroll
    for (int mi = 0; mi < 8; ++mi) {
        #pragma unroll
        for (int r = 0; r < 4; ++r) {
            const int m = m0 + wr * 128 + (mi >> 2) * 64 + (mi & 3) * 16 + rr4 + r;
            const float pgv = p_gen[m];
            #pragma unroll
            for (int nj = 0; nj < 4; ++nj) {
                const int n = n0 + wc * 64 + nj * 16 + rq;
                out[(size_t)m * V_DIM + n] = pgv * (acc[mi][nj][r] + bias[n]);
            }
        }
    }
}

// ---------------- scatter: out[t,b,post[s,b]] += (1-pg[t,b]) * att[t,b,s] ----------------

__global__ void scatter_att(const float* __restrict__ att, const float* __restrict__ p_gen,
                            const int* __restrict__ post, float* __restrict__ out) {
    const int tb = blockIdx.x;             // t*B + b
    const int b = tb & (B_DIM - 1);
    const float g = 1.0f - p_gen[tb];
    float* o = out + (size_t)tb * V_DIM;
    const float* a = att + (size_t)tb * S_DIM;
    for (int s = threadIdx.x; s < S_DIM; s += blockDim.x) {
        atomicAdd(&o[post[s * B_DIM + b]], g * a[s]);
    }
}

// ---------------- fallback (ws too small): fp32 vector GEMM ----------------

#define FB_MT 16
__global__ __launch_bounds__(256)
void gemm_naive(const float* __restrict__ h, const float* __restrict__ W,
                const float* __restrict__ bias, const float* __restrict__ pg,
                float* __restrict__ out) {
    const int mb = blockIdx.y;
    const int v = blockIdx.x * 256 + threadIdx.x;
    __shared__ float hs[FB_MT][128];
    float acc[FB_MT] = {};
    for (int k0 = 0; k0 < D_DIM; k0 += 128) {
        for (int i = threadIdx.x; i < FB_MT * 128; i += 256)
            hs[i >> 7][i & 127] = h[(size_t)(mb * FB_MT + (i >> 7)) * D_DIM + k0 + (i & 127)];
        __syncthreads();
        for (int kk = 0; kk < 128; ++kk) {
            const float wv = W[(size_t)(k0 + kk) * V_DIM + v];
            #pragma unroll
            for (int i = 0; i < FB_MT; ++i) acc[i] += hs[i][kk] * wv;
        }
        __syncthreads();
    }
    #pragma unroll
    for (int i = 0; i < FB_MT; ++i) {
        const int m = mb * FB_MT + i;
        out[(size_t)m * V_DIM + v] = pg[m] * (acc[i] + bias[v]);
    }
}

// ---------------- launcher ----------------

extern "C" void kernel_launch(void* const* d_in, const int* in_sizes, int n_in,
                              void* d_out, int out_size, void* d_ws, size_t ws_size,
                              hipStream_t stream) {
    const float* h    = (const float*)d_in[0];   // (T,B,D)
    const float* W    = (const float*)d_in[1];   // (D,V)
    const float* bias = (const float*)d_in[2];   // (V,)
    const float* att  = (const float*)d_in[3];   // (T,B,S)
    const float* pg   = (const float*)d_in[4];   // (T,B,1)
    const int*   post = (const int*)d_in[5];     // (S,B)
    float* out = (float*)d_out;                  // (T,B,V) fp32

    const size_t wt_bytes = (size_t)V_DIM * D_DIM * 2;   // 98,304,000
    const size_t hb_bytes = (size_t)M_DIM * D_DIM * 2;   //  6,291,456

    if (ws_size >= wt_bytes + hb_bytes) {
        unsigned short* Wt = (unsigned short*)d_ws;
        unsigned short* hb = (unsigned short*)((char*)d_ws + wt_bytes);
        dim3 tg(D_DIM / 64, V_DIM / 64);   // 24 x 500
        convT_W_h<<<tg, 256, 0, stream>>>(W, Wt, h, hb);
        gemm_8phase<<<(M_DIM / BM3) * (V_DIM / BN3), 512, 0, stream>>>(hb, Wt, bias, pg, out);
    } else {
        dim3 fg(V_DIM / 256, M_DIM / FB_MT);
        gemm_naive<<<fg, 256, 0, stream>>>(h, W, bias, pg, out);
    }

    scatter_att<<<M_DIM, 256, 0, stream>>>(att, pg, post, out);
}